// Round 3
// baseline (363.005 us; speedup 1.0000x reference)
//
#include <hip/hip_runtime.h>

// Conv1d with mean + threshold channels, fused single kernel.
// x: [64, 1, 100000] f32 ; W: [62, 1, 19] f32 ; b: [62] f32
// out: [64, 64, 20000] f32  (ch0 = windowed mean, ch1 = threshold flag, ch2..63 = conv)

#define BATCH       64
#define LIN         100000
#define LOUT        20000
#define KSZ         19
#define STRIDE_     5
#define PAD_        9
#define CSTD        62          // standard conv output channels
#define UPPER_      2.99f
#define LOWER_      (-2.99f)

#define TPB         256
#define POS_PER_BLK 512                         // 2 positions per thread
#define BPR         ((LOUT + POS_PER_BLK - 1) / POS_PER_BLK)   // blocks per batch row = 40
#define TILE_IN     ((POS_PER_BLK - 1) * STRIDE_ + KSZ)        // 2574 floats
#define WROW        20                          // padded weight row (16B-aligned rows)

__global__ __launch_bounds__(TPB)
void conv1d_mean_thr_kernel(const float* __restrict__ x,
                            const float* __restrict__ W,
                            const float* __restrict__ bias,
                            float* __restrict__ out)
{
    __shared__ float tile[TILE_IN];
    __shared__ float wsh[CSTD * WROW];
    __shared__ float bsh[CSTD];

    const int tid   = threadIdx.x;
    const int blk   = blockIdx.x;
    const int batch = blk / BPR;
    const int pblk  = blk - batch * BPR;
    const int p0    = pblk * POS_PER_BLK;
    const long tstart = (long)p0 * STRIDE_ - PAD_;

    // ---- stage input tile (zero-fill outside [0, LIN)) ----
    const float* xrow = x + (size_t)batch * LIN;
    for (int i = tid; i < TILE_IN; i += TPB) {
        long g = tstart + i;
        tile[i] = (g >= 0 && g < LIN) ? xrow[g] : 0.0f;
    }
    // ---- stage weights (padded rows) + bias ----
    for (int i = tid; i < CSTD * WROW; i += TPB) {
        int c = i / WROW, k = i - c * WROW;
        wsh[i] = (k < KSZ) ? W[c * KSZ + k] : 0.0f;
    }
    if (tid < CSTD) bsh[tid] = bias[tid];
    __syncthreads();

    // ---- per-thread windows in registers ----
    float xv0[KSZ], xv1[KSZ];
    const int l0 = tid * STRIDE_;
    const int l1 = (tid + TPB) * STRIDE_;
#pragma unroll
    for (int k = 0; k < KSZ; ++k) {
        xv0[k] = tile[l0 + k];
        xv1[k] = tile[l1 + k];
    }

    const int pos0 = p0 + tid;
    const int pos1 = pos0 + TPB;
    const bool v0 = (pos0 < LOUT);
    const bool v1 = (pos1 < LOUT);
    float* orow = out + (size_t)batch * 64 * LOUT;

    // ---- channel 0 (mean) and channel 1 (threshold) ----
    float s0 = 0.f, s1 = 0.f;
    float mx0 = -INFINITY, mx1 = -INFINITY;
    float mn0 =  INFINITY, mn1 =  INFINITY;
#pragma unroll
    for (int k = 0; k < KSZ; ++k) {
        s0 += xv0[k]; mx0 = fmaxf(mx0, xv0[k]); mn0 = fminf(mn0, xv0[k]);
        s1 += xv1[k]; mx1 = fmaxf(mx1, xv1[k]); mn1 = fminf(mn1, xv1[k]);
    }
    const float inv_k = 1.0f / (float)KSZ;
    float thr0 = (mx0 > UPPER_) ? 1.0f : ((mn0 < LOWER_) ? -1.0f : 0.0f);
    float thr1 = (mx1 > UPPER_) ? 1.0f : ((mn1 < LOWER_) ? -1.0f : 0.0f);
    if (v0) { orow[pos0] = s0 * inv_k; orow[LOUT + pos0] = thr0; }
    if (v1) { orow[pos1] = s1 * inv_k; orow[LOUT + pos1] = thr1; }

    // ---- channels 2..63: standard conv ----
    for (int c = 0; c < CSTD; ++c) {
        const float* wr = &wsh[c * WROW];
        float acc0 = 0.f, acc1 = 0.f;
#pragma unroll
        for (int k = 0; k < KSZ; ++k) {
            float wv = wr[k];
            acc0 = fmaf(xv0[k], wv, acc0);
            acc1 = fmaf(xv1[k], wv, acc1);
        }
        const float bv = bsh[c];
        size_t cbase = (size_t)(c + 2) * LOUT;
        if (v0) orow[cbase + pos0] = acc0 + bv;
        if (v1) orow[cbase + pos1] = acc1 + bv;
    }
}

extern "C" void kernel_launch(void* const* d_in, const int* in_sizes, int n_in,
                              void* d_out, int out_size, void* d_ws, size_t ws_size,
                              hipStream_t stream)
{
    const float* x    = (const float*)d_in[0];
    const float* W    = (const float*)d_in[1];
    const float* bias = (const float*)d_in[2];
    float* out        = (float*)d_out;

    dim3 grid(BATCH * BPR);
    dim3 block(TPB);
    conv1d_mean_thr_kernel<<<grid, block, 0, stream>>>(x, W, bias, out);
}